// Round 12
// baseline (395.555 us; speedup 1.0000x reference)
//
#include <hip/hip_runtime.h>

typedef short s16x8 __attribute__((ext_vector_type(8)));
typedef float f32x4 __attribute__((ext_vector_type(4)));

#define DIM     512
#define BATCH   256
#define NTRI    131328          // (512*512+512)/2
#define FDIM    131840          // 512 + NTRI
#define KBLOCKS 2060            // FDIM / 64
#define BNW     256             // N per wg
#define NTILES  2               // 512 / BNW
#define CCH     128             // K-chunks: grid 2*128=256 = 1 wg/CU

__device__ __forceinline__ unsigned short f2bf(float f) {
  __bf16 h = (__bf16)f;                       // RNE hardware cvt
  return __builtin_bit_cast(unsigned short, h);
}
__device__ __forceinline__ float bf2f(unsigned short s) {
  union { unsigned u; float f; } v; v.u = (unsigned)s << 16; return v.f;
}
__device__ __forceinline__ unsigned pk2(float a, float b) {
  return (unsigned)f2bf(a) | ((unsigned)f2bf(b) << 16);
}
__device__ __forceinline__ int swz(int m) { return (m ^ (m >> 2)) & 7; }
#define SB() __builtin_amdgcn_sched_barrier(0)

// ---------- setup: pair table (blocks 0..511) + x transpose (blocks 512..1023) ----------
__global__ void setup(unsigned* __restrict__ table, const float* __restrict__ x,
                      unsigned short* __restrict__ Xt) {
  int bid = blockIdx.x;
  if (bid < 512) {
    int i = bid;
    int base = i * DIM - (i * (i - 1)) / 2;
    int len = DIM - i;
    for (int t = threadIdx.x; t < len; t += blockDim.x)
      table[base + t] = ((unsigned)i << 16) | (unsigned)(i + t);
  } else {
    int t = (bid - 512) * blockDim.x + threadIdx.x;   // 131072
    int r = t & (BATCH - 1);
    int c = t >> 8;
    Xt[c * BATCH + r] = f2bf(x[r * DIM + c]);
  }
}

// ---------- fused GEMM: in-kernel featgen -> As, W -> dbuf Ws, 1 barrier/iter ----------
// wg: M=256 x N=256 x K-slice. 16 waves = 4 wm x 4 wn, per wave 64x64, acc 4x4 f32x4.
__global__ __launch_bounds__(1024)
void qgemm(const unsigned* __restrict__ table,
           const unsigned short* __restrict__ Xt,    // [512][256] bf16 (x or h, transposed)
           const float* __restrict__ W,              // [512][131840] f32
           unsigned short* __restrict__ partial,     // [C][256][512] bf16
           int C)
{
  __shared__ char As[2][8 * 4128];              // 2 x 33 KB feature tiles (staggered [g][m])
  __shared__ unsigned short Ws[2][BNW * 64];    // 2 x 32 KB weight tiles (swizzled)
  const int chunk = blockIdx.x % C;
  const int ntile = blockIdx.x / C;
  const int kb0 = (KBLOCKS * chunk) / C;
  const int kb1 = (KBLOCKS * (chunk + 1)) / C;
  const int n0 = ntile * BNW;
  const int tid = threadIdx.x;
  const int lane = tid & 63;
  const int wave = tid >> 6;                    // 0..15
  const int wm = wave & 3;                      // 4 waves along M (64 rows)
  const int wn = wave >> 2;                     // 4 waves along N (64 cols)
  const int lm = lane & 15;
  const int lk = lane >> 4;

  const int wr0 = tid >> 4;                     // Ws staging: 16 lanes = 256B of one W row
  const int wc16 = tid & 15;
  const int m = tid & 255;                      // featgen: fixed batch row per thread
  const int gb = tid >> 8;                      // featgen: g = gb + 4p (wave-uniform)

  f32x4 acc[4][4] = {};                         // [mf][nf]
  f32x4 wrN[4];

  const float* wp0 = W + (size_t)(n0 + wr0) * FDIM + wc16 * 4;
  const size_t wrow64 = (size_t)64 * FDIM;

  // generate one 16B feature unit (8 bf16) for k-group g of tile kb, batch row m
  auto fgen = [&](int kb, int g) -> uint4 {
    int f0 = kb * 64 + g * 8;
    if (f0 < DIM) {                             // linear features (kb < 8)
      unsigned short v[8];
      #pragma unroll
      for (int e = 0; e < 8; ++e) v[e] = Xt[(f0 + e) * BATCH + m];
      return make_uint4((unsigned)v[0] | ((unsigned)v[1] << 16),
                        (unsigned)v[2] | ((unsigned)v[3] << 16),
                        (unsigned)v[4] | ((unsigned)v[5] << 16),
                        (unsigned)v[6] | ((unsigned)v[7] << 16));
    }
    int p0 = f0 - DIM;
    unsigned t0 = table[p0], t7 = table[p0 + 7];
    float pr[8];
    if ((t0 >> 16) == (t7 >> 16)) {             // fast path: same i, contiguous j
      float xi = bf2f(Xt[(t0 >> 16) * BATCH + m]);
      int j0 = (int)(t0 & 0xffffu);
      #pragma unroll
      for (int e = 0; e < 8; ++e) pr[e] = xi * bf2f(Xt[(j0 + e) * BATCH + m]);
    } else {                                    // run boundary (rare, wave-uniform)
      #pragma unroll
      for (int e = 0; e < 8; ++e) {
        unsigned ij = table[p0 + e];
        pr[e] = bf2f(Xt[(ij >> 16) * BATCH + m]) * bf2f(Xt[(ij & 0xffffu) * BATCH + m]);
      }
    }
    return make_uint4(pk2(pr[0], pr[1]), pk2(pr[2], pr[3]),
                      pk2(pr[4], pr[5]), pk2(pr[6], pr[7]));
  };
  auto stageA = [&](int kb, int buf) {          // 2 units/thread -> staggered [g][m] layout
    #pragma unroll
    for (int p = 0; p < 2; ++p) {
      int g = gb + 4 * p;
      uint4 v = fgen(kb, g);
      *(uint4*)(&As[buf][g * 4128 + m * 16]) = v;
    }
  };
  auto loadWr = [&](f32x4* w, int kb) {         // 4 dwordx4/thread, 4 rows/wave-inst coalesced
    #pragma unroll
    for (int it = 0; it < 4; ++it)
      w[it] = *(const f32x4*)(wp0 + it * wrow64 + (size_t)kb * 64);
  };
  auto storeWs = [&](int buf, const f32x4* w) {
    #pragma unroll
    for (int it = 0; it < 4; ++it) {
      int r = wr0 + it * 64;                    // 0..255
      int slot = (wc16 >> 1) ^ swz(r);
      *(uint2*)((char*)&Ws[buf][0] + r * 128 + slot * 16 + (wc16 & 1) * 8) =
          make_uint2(pk2(w[it][0], w[it][1]), pk2(w[it][2], w[it][3]));
    }
  };
  auto compute = [&](int buf) {
    #pragma unroll
    for (int ks = 0; ks < 2; ++ks) {
      s16x8 bfr[4], afr[4];
      #pragma unroll
      for (int nf = 0; nf < 4; ++nf) {
        int n = wn * 64 + nf * 16 + lm;         // 0..255
        int slot = (ks * 4 + lk) ^ swz(n);
        bfr[nf] = *(const s16x8*)((const char*)&Ws[buf][0] + n * 128 + slot * 16);
      }
      #pragma unroll
      for (int mf = 0; mf < 4; ++mf)
        afr[mf] = *(const s16x8*)(&As[buf][(ks * 4 + lk) * 4128 + (wm * 64 + mf * 16 + lm) * 16]);
      __builtin_amdgcn_s_setprio(1);
      #pragma unroll
      for (int mf = 0; mf < 4; ++mf)
        #pragma unroll
        for (int nf = 0; nf < 4; ++nf)
          acc[mf][nf] = __builtin_amdgcn_mfma_f32_16x16x32_bf16(afr[mf], bfr[nf], acc[mf][nf], 0, 0, 0);
      __builtin_amdgcn_s_setprio(0);
    }
  };

  // ---- prologue: stage tile kb0 into buf 0; prefetch W(kb0+1) ----
  {
    f32x4 wT[4];
    loadWr(wT, kb0);
    stageA(kb0, 0);
    storeWs(0, wT);                             // compiler inserts counted vmcnt for wT
    loadWr(wrN, min(kb0 + 1, KBLOCKS - 1));
    asm volatile("s_waitcnt lgkmcnt(0)" ::: "memory"); SB();
    __builtin_amdgcn_s_barrier();
  }

  // ---- steady loop: compute(t) while staging t+1 into the other buffer ----
  for (int kb = kb0; kb < kb1 - 1; ++kb) {
    const int buf = (kb - kb0) & 1;
    stageA(kb + 1, buf ^ 1);                    // Xt gathers + VALU + ds_write
    storeWs(buf ^ 1, wrN);                      // counted vmcnt: wrN loaded a full iter ago
    loadWr(wrN, min(kb + 2, KBLOCKS - 1));      // issue next W; lands during next compute
    compute(buf);
    asm volatile("s_waitcnt lgkmcnt(0)" ::: "memory"); SB();
    __builtin_amdgcn_s_barrier();               // single barrier; VMEM stays in flight
  }

  // ---- last tile ----
  compute((kb1 - 1 - kb0) & 1);

  // ---- write partial tile (bf16) ----
  unsigned short* pout = partial + (size_t)chunk * (BATCH * DIM);
  #pragma unroll
  for (int mf = 0; mf < 4; ++mf) {
    #pragma unroll
    for (int nf = 0; nf < 4; ++nf) {
      int mrow = wm * 64 + mf * 16 + lk * 4;    // C/D: col=lane&15, row=(lane>>4)*4+reg
      int ncol = n0 + wn * 64 + nf * 16 + lm;
      #pragma unroll
      for (int r = 0; r < 4; ++r)
        pout[(size_t)(mrow + r) * DIM + ncol] = f2bf(acc[mf][nf][r]);
    }
  }
}

// ---------- reductions (bf16 partials, uint4 = 8 elems per load) ----------
__global__ void reduce_h(const unsigned short* __restrict__ partial, const float* __restrict__ bias,
                         unsigned short* __restrict__ Ht, int C) {
  int u = blockIdx.x * blockDim.x + threadIdx.x;   // 16384
  int t8 = u * 8;                                  // t = b*512 + o
  int b = t8 >> 9;
  int o0 = t8 & (DIM - 1);
  float s[8];
  #pragma unroll
  for (int e = 0; e < 8; ++e) s[e] = bias[o0 + e];
  for (int c = 0; c < C; ++c) {
    uint4 v = *(const uint4*)(partial + (size_t)c * (BATCH * DIM) + t8);
    unsigned w[4] = {v.x, v.y, v.z, v.w};
    #pragma unroll
    for (int p = 0; p < 4; ++p) {
      s[2*p]   += bf2f((unsigned short)(w[p] & 0xffffu));
      s[2*p+1] += bf2f((unsigned short)(w[p] >> 16));
    }
  }
  #pragma unroll
  for (int e = 0; e < 8; ++e)
    Ht[(o0 + e) * BATCH + b] = f2bf(s[e]);         // transposed bf16 for layer-2 featgen
}

__global__ void reduce_out(const unsigned short* __restrict__ partial, const float* __restrict__ bias,
                           float* __restrict__ out, int C) {
  int u = blockIdx.x * blockDim.x + threadIdx.x;   // 16384
  int t8 = u * 8;
  int o0 = t8 & (DIM - 1);
  float s[8];
  #pragma unroll
  for (int e = 0; e < 8; ++e) s[e] = bias[o0 + e];
  for (int c = 0; c < C; ++c) {
    uint4 v = *(const uint4*)(partial + (size_t)c * (BATCH * DIM) + t8);
    unsigned w[4] = {v.x, v.y, v.z, v.w};
    #pragma unroll
    for (int p = 0; p < 4; ++p) {
      s[2*p]   += bf2f((unsigned short)(w[p] & 0xffffu));
      s[2*p+1] += bf2f((unsigned short)(w[p] >> 16));
    }
  }
  f32x4 lo = {s[0], s[1], s[2], s[3]};
  f32x4 hi = {s[4], s[5], s[6], s[7]};
  *(f32x4*)(out + t8) = lo;
  *(f32x4*)(out + t8 + 4) = hi;
}

extern "C" void kernel_launch(void* const* d_in, const int* in_sizes, int n_in,
                              void* d_out, int out_size, void* d_ws, size_t ws_size,
                              hipStream_t stream) {
  const float* x  = (const float*)d_in[0];
  const float* W0 = (const float*)d_in[1];
  const float* b0 = (const float*)d_in[2];
  const float* W1 = (const float*)d_in[3];
  const float* b1 = (const float*)d_in[4];
  float* out = (float*)d_out;

  char* ws = (char*)d_ws;
  unsigned* table    = (unsigned*)ws;                        // 525,312 B
  unsigned short* Xt = (unsigned short*)(ws + 525312);       // 262,144 B
  unsigned short* Ht = (unsigned short*)(ws + 787456);       // 262,144 B
  unsigned short* partial = (unsigned short*)(ws + 1049600); // C * 256 KiB (bf16)

  size_t avail = (ws_size > 1049600) ? (ws_size - 1049600) : 0;
  int C = (int)(avail / ((size_t)BATCH * DIM * sizeof(unsigned short)));
  if (C > CCH) C = CCH;
  if (C < 1)  C = 1;

  setup<<<dim3(1024), dim3(256), 0, stream>>>(table, x, Xt);

  qgemm<<<dim3(NTILES * C), dim3(1024), 0, stream>>>(table, Xt, W0, partial, C);
  reduce_h<<<dim3(64), dim3(256), 0, stream>>>(partial, b0, Ht, C);

  qgemm<<<dim3(NTILES * C), dim3(1024), 0, stream>>>(table, Ht, W1, partial, C);
  reduce_out<<<dim3(64), dim3(256), 0, stream>>>(partial, b1, out, C);
}

// Round 13
// 264.325 us; speedup vs baseline: 1.4965x; 1.4965x over previous
//
#include <hip/hip_runtime.h>

typedef short s16x8 __attribute__((ext_vector_type(8)));
typedef float f32x4 __attribute__((ext_vector_type(4)));

#define DIM     512
#define BATCH   256
#define NTRI    131328          // (512*512+512)/2
#define FDIM    131840          // 512 + NTRI
#define KBLOCKS 2060            // FDIM / 64
#define KSUP    515             // KBLOCKS / 4 (super-tiles of 256 k)
#define BN      64
#define NTILES  8               // 512 / BN
#define CCH     64              // K-chunks: grid 8*64=512 = 2 wg/CU, %8==0

__device__ __forceinline__ unsigned short f2bf(float f) {
  __bf16 h = (__bf16)f;                       // RNE hardware cvt
  return __builtin_bit_cast(unsigned short, h);
}
__device__ __forceinline__ float bf2f(unsigned short s) {
  union { unsigned u; float f; } v; v.u = (unsigned)s << 16; return v.f;
}
__device__ __forceinline__ unsigned pk2(float a, float b) {
  return (unsigned)f2bf(a) | ((unsigned)f2bf(b) << 16);
}
__device__ __forceinline__ int swz(int m) { return (m ^ (m >> 2)) & 7; }

// ---------- setup: pair table (blocks 0..511) + x transpose (blocks 512..1023) ----------
__global__ void setup(unsigned* __restrict__ table, const float* __restrict__ x,
                      unsigned short* __restrict__ Xt) {
  int bid = blockIdx.x;
  if (bid < 512) {
    int i = bid;
    int base = i * DIM - (i * (i - 1)) / 2;
    int len = DIM - i;
    for (int t = threadIdx.x; t < len; t += blockDim.x)
      table[base + t] = ((unsigned)i << 16) | (unsigned)(i + t);
  } else {
    int t = (bid - 512) * blockDim.x + threadIdx.x;   // 131072
    int r = t & (BATCH - 1);
    int c = t >> 8;
    Xt[c * BATCH + r] = f2bf(x[r * DIM + c]);
  }
}

// ---------- feature materialization: dense [kb][g][m] 16B units, direct coalesced store ----------
__global__ __launch_bounds__(512)
void featgen(const unsigned* __restrict__ table,
             const unsigned short* __restrict__ Xt,   // [512][256] bf16
             uint4* __restrict__ Feat)                // [KBLOCKS][8][256] uint4
{
  const int kb = blockIdx.x;
  const int tid = threadIdx.x;
  const int s8 = tid >> 6;                     // wave-uniform k-group g
  const int lane = tid & 63;
  const int f0 = kb * 64 + s8 * 8;
  uint4* out = Feat + ((size_t)kb * 8 + s8) * 256;

  if (f0 < DIM) {                              // linear features (kb < 8)
    #pragma unroll
    for (int mb = 0; mb < 4; ++mb) {
      int m = mb * 64 + lane;
      unsigned short v[8];
      #pragma unroll
      for (int e = 0; e < 8; ++e) v[e] = Xt[(f0 + e) * BATCH + m];
      uint4 pk;
      pk.x = (unsigned)v[0] | ((unsigned)v[1] << 16);
      pk.y = (unsigned)v[2] | ((unsigned)v[3] << 16);
      pk.z = (unsigned)v[4] | ((unsigned)v[5] << 16);
      pk.w = (unsigned)v[6] | ((unsigned)v[7] << 16);
      out[m] = pk;
    }
  } else {
    int p0 = f0 - DIM;
    unsigned t0 = table[p0], t7 = table[p0 + 7];
    if ((t0 >> 16) == (t7 >> 16)) {            // fast path: same i, contiguous j
      int i = (int)(t0 >> 16), j0 = (int)(t0 & 0xffffu);
      #pragma unroll
      for (int mb = 0; mb < 4; ++mb) {
        int m = mb * 64 + lane;
        float xi = bf2f(Xt[i * BATCH + m]);
        float pr[8];
        #pragma unroll
        for (int e = 0; e < 8; ++e) pr[e] = xi * bf2f(Xt[(j0 + e) * BATCH + m]);
        out[m] = make_uint4(pk2(pr[0], pr[1]), pk2(pr[2], pr[3]),
                            pk2(pr[4], pr[5]), pk2(pr[6], pr[7]));
      }
    } else {                                   // run boundary (rare)
      unsigned tt[8];
      #pragma unroll
      for (int e = 0; e < 8; ++e) tt[e] = table[p0 + e];
      #pragma unroll
      for (int mb = 0; mb < 4; ++mb) {
        int m = mb * 64 + lane;
        float pr[8];
        #pragma unroll
        for (int e = 0; e < 8; ++e)
          pr[e] = bf2f(Xt[(tt[e] >> 16) * BATCH + m]) * bf2f(Xt[(tt[e] & 0xffffu) * BATCH + m]);
        out[m] = make_uint4(pk2(pr[0], pr[1]), pk2(pr[2], pr[3]),
                            pk2(pr[4], pr[5]), pk2(pr[6], pr[7]));
      }
    }
  }
}

// ---------- GEMM: BK=256 super-tiles; W 1KB/row sweeps; 1 barrier per 4 kb ----------
// 8 waves, wave = 32 M-rows, all 64 N-cols. A fragments register-direct from Feat.
__global__ __launch_bounds__(512, 4)
void qgemm(const uint4* __restrict__ Feat,      // dense [kb][g][m] 16B units
           const float* __restrict__ W,         // [512][131840] f32
           unsigned short* __restrict__ partial, // [C][256][512] bf16
           int C)
{
  __shared__ unsigned short Ws[2][16384];       // 2 x 32 KB: [block j 0..3][row 0..63][slot]
  const int chunk = blockIdx.x % C;             // chunk's 8 ntiles share an XCD
  const int ntile = blockIdx.x / C;
  const int sp0 = (KSUP * chunk) / C;
  const int sp1 = (KSUP * (chunk + 1)) / C;
  const int n0 = ntile * BN;
  const int tid = threadIdx.x;
  const int lane = tid & 63;
  const int wave = tid >> 6;                    // 0..7 -> rows [wave*32, wave*32+32)
  const int lm = lane & 15;
  const int lk = lane >> 4;

  const int wr = tid >> 4;                      // W staging: row 0..31 (+32), 16 lanes/row
  const int wc = tid & 15;

  f32x4 acc[2][4] = {};                         // [mf][nf]
  uint4 aA[2][2], aB[2][2];                     // [mf][ks] ping-pong, static names

  const float* wp0 = W + (size_t)(n0 + wr) * FDIM + wc * 4;
  const size_t wrow32 = (size_t)32 * FDIM;
  // afr unit index: kb*2048 + (ks*4+lk)*256 + (wave*32 + mf*16 + lm)
  const int abase = lk * 256 + wave * 32 + lm;

  auto loadA = [&](uint4 (*a)[2], int kb) {
    #pragma unroll
    for (int mf = 0; mf < 2; ++mf)
      #pragma unroll
      for (int ks = 0; ks < 2; ++ks)
        a[mf][ks] = Feat[(size_t)kb * 2048 + ks * 1024 + mf * 16 + abase];
  };
  // 8 dwordx4: rows wr,wr+32; 4 insts/row sweep 1KB contiguous (256B per wave-inst)
  auto loadW = [&](f32x4* w, int sp) {
    const float* base = wp0 + (size_t)sp * 256;
    #pragma unroll
    for (int h = 0; h < 2; ++h)
      #pragma unroll
      for (int i = 0; i < 4; ++i)
        w[h * 4 + i] = *(const f32x4*)(base + h * wrow32 + i * 64);
  };
  auto storeWs = [&](int buf, const f32x4* w) { // reg i -> k-block i, cols wc*4..+3
    #pragma unroll
    for (int h = 0; h < 2; ++h) {
      int r = wr + h * 32;
      int slot = (wc >> 1) ^ swz(r);
      #pragma unroll
      for (int i = 0; i < 4; ++i)
        *(uint2*)((char*)&Ws[buf][0] + i * 8192 + r * 128 + slot * 16 + (wc & 1) * 8) =
            make_uint2(pk2(w[h*4+i][0], w[h*4+i][1]), pk2(w[h*4+i][2], w[h*4+i][3]));
    }
  };
  auto computeSub = [&](int buf, int j, const uint4 (*a)[2]) {
    #pragma unroll
    for (int ks = 0; ks < 2; ++ks) {
      s16x8 bfr[4];
      #pragma unroll
      for (int nf = 0; nf < 4; ++nf) {
        int n = nf * 16 + lm;
        int slot = (ks * 4 + lk) ^ swz(n);
        bfr[nf] = *(const s16x8*)((const char*)&Ws[buf][0] + j * 8192 + n * 128 + slot * 16);
      }
      __builtin_amdgcn_s_setprio(1);
      #pragma unroll
      for (int mf = 0; mf < 2; ++mf)
        #pragma unroll
        for (int nf = 0; nf < 4; ++nf)
          acc[mf][nf] = __builtin_amdgcn_mfma_f32_16x16x32_bf16(
              __builtin_bit_cast(s16x8, a[mf][ks]), bfr[nf], acc[mf][nf], 0, 0, 0);
      __builtin_amdgcn_s_setprio(0);
    }
  };

  // ---- prologue: Ws[sp0&1] = W(sp0); aA = A(sp0*4) ----
  {
    f32x4 w0[8];
    loadW(w0, sp0);
    loadA(aA, sp0 * 4);
    storeWs(sp0 & 1, w0);                       // compiler-counted vmcnt for w0 only
    asm volatile("s_waitcnt lgkmcnt(0)" ::: "memory");
    __builtin_amdgcn_s_barrier();
  }

  // ---- super loop: 4 sub-iters per barrier ----
  for (int sp = sp0; sp < sp1; ++sp) {
    const int buf = sp & 1;
    const int kb = sp * 4;
    f32x4 wn[8];
    loadW(wn, min(sp + 1, KSUP - 1));           // issued early; lands during 4 subs
    loadA(aB, kb + 1); computeSub(buf, 0, aA);
    loadA(aA, kb + 2); computeSub(buf, 1, aB);
    loadA(aB, kb + 3); computeSub(buf, 2, aA);
    loadA(aA, min(kb + 4, KBLOCKS - 1)); computeSub(buf, 3, aB);
    storeWs(buf ^ 1, wn);                       // counted wait: wn issued ~4 subs ago
    asm volatile("s_waitcnt lgkmcnt(0)" ::: "memory");
    __builtin_amdgcn_s_barrier();               // ONE barrier per 4 kb
  }

  // ---- write partial tile (bf16) ----
  unsigned short* pout = partial + (size_t)chunk * (BATCH * DIM);
  #pragma unroll
  for (int mf = 0; mf < 2; ++mf) {
    #pragma unroll
    for (int nf = 0; nf < 4; ++nf) {
      int mrow = wave * 32 + mf * 16 + lk * 4;  // C/D: col=lane&15, row=(lane>>4)*4+reg
      int ncol = n0 + nf * 16 + lm;
      #pragma unroll
      for (int r = 0; r < 4; ++r)
        pout[(size_t)(mrow + r) * DIM + ncol] = f2bf(acc[mf][nf][r]);
    }
  }
}

// ---------- reductions (bf16 partials, uint4 = 8 elems per load) ----------
__global__ void reduce_h(const unsigned short* __restrict__ partial, const float* __restrict__ bias,
                         unsigned short* __restrict__ Ht, int C) {
  int u = blockIdx.x * blockDim.x + threadIdx.x;   // 16384
  int t8 = u * 8;                                  // t = b*512 + o
  int b = t8 >> 9;
  int o0 = t8 & (DIM - 1);
  float s[8];
  #pragma unroll
  for (int e = 0; e < 8; ++e) s[e] = bias[o0 + e];
  for (int c = 0; c < C; ++c) {
    uint4 v = *(const uint4*)(partial + (size_t)c * (BATCH * DIM) + t8);
    unsigned w[4] = {v.x, v.y, v.z, v.w};
    #pragma unroll
    for (int p = 0; p < 4; ++p) {
      s[2*p]   += bf2f((unsigned short)(w[p] & 0xffffu));
      s[2*p+1] += bf2f((unsigned short)(w[p] >> 16));
    }
  }
  #pragma unroll
  for (int e = 0; e < 8; ++e)
    Ht[(o0 + e) * BATCH + b] = f2bf(s[e]);         // transposed bf16 for layer-2 featgen
}

__global__ void reduce_out(const unsigned short* __restrict__ partial, const float* __restrict__ bias,
                           float* __restrict__ out, int C) {
  int u = blockIdx.x * blockDim.x + threadIdx.x;   // 16384
  int t8 = u * 8;
  int o0 = t8 & (DIM - 1);
  float s[8];
  #pragma unroll
  for (int e = 0; e < 8; ++e) s[e] = bias[o0 + e];
  for (int c = 0; c < C; ++c) {
    uint4 v = *(const uint4*)(partial + (size_t)c * (BATCH * DIM) + t8);
    unsigned w[4] = {v.x, v.y, v.z, v.w};
    #pragma unroll
    for (int p = 0; p < 4; ++p) {
      s[2*p]   += bf2f((unsigned short)(w[p] & 0xffffu));
      s[2*p+1] += bf2f((unsigned short)(w[p] >> 16));
    }
  }
  f32x4 lo = {s[0], s[1], s[2], s[3]};
  f32x4 hi = {s[4], s[5], s[6], s[7]};
  *(f32x4*)(out + t8) = lo;
  *(f32x4*)(out + t8 + 4) = hi;
}

extern "C" void kernel_launch(void* const* d_in, const int* in_sizes, int n_in,
                              void* d_out, int out_size, void* d_ws, size_t ws_size,
                              hipStream_t stream) {
  const float* x  = (const float*)d_in[0];
  const float* W0 = (const float*)d_in[1];
  const float* b0 = (const float*)d_in[2];
  const float* W1 = (const float*)d_in[3];
  const float* b1 = (const float*)d_in[4];
  float* out = (float*)d_out;

  char* ws = (char*)d_ws;
  unsigned* table    = (unsigned*)ws;                        // 525,312 B
  unsigned short* Xt = (unsigned short*)(ws + 525312);       // 262,144 B
  unsigned short* Ht = (unsigned short*)(ws + 787456);       // 262,144 B
  uint4* Feat        = (uint4*)(ws + 1049600);               // 67,502,080 B (2060*32KB)
  size_t feat_end    = 1049600 + (size_t)KBLOCKS * 32768;
  unsigned short* partial = (unsigned short*)(ws + feat_end); // C * 256 KiB (bf16)

  size_t avail = (ws_size > feat_end) ? (ws_size - feat_end) : 0;
  int C = (int)(avail / ((size_t)BATCH * DIM * sizeof(unsigned short)));
  if (C > CCH) C = CCH;
  if (C < 1)  C = 1;

  setup<<<dim3(1024), dim3(256), 0, stream>>>(table, x, Xt);

  featgen<<<dim3(KBLOCKS), dim3(512), 0, stream>>>(table, Xt, Feat);
  qgemm<<<dim3(NTILES * C), dim3(512), 0, stream>>>(Feat, W0, partial, C);
  reduce_h<<<dim3(64), dim3(256), 0, stream>>>(partial, b0, Ht, C);

  featgen<<<dim3(KBLOCKS), dim3(512), 0, stream>>>(table, Ht, Feat);
  qgemm<<<dim3(NTILES * C), dim3(512), 0, stream>>>(Feat, W1, partial, C);
  reduce_out<<<dim3(64), dim3(256), 0, stream>>>(partial, b1, out, C);
}